// Round 7
// baseline (969.432 us; speedup 1.0000x reference)
//
#include <hip/hip_runtime.h>
#include <hip/hip_bf16.h>

#define NUM_STEPS 10
#define DT 0.1f
#define BK 64

typedef __bf16 bf16_t;
typedef __bf16 bf16x8 __attribute__((ext_vector_type(8)));
typedef __bf16 bf16x4 __attribute__((ext_vector_type(4)));
typedef float f32x4 __attribute__((ext_vector_type(4)));

__global__ void cvt_f32_to_bf16(const float* __restrict__ in,
                                bf16_t* __restrict__ out, int n4) {
  int i = blockIdx.x * blockDim.x + threadIdx.x;
  if (i < n4) {
    float4 v = ((const float4*)in)[i];
    bf16x4 o = {(bf16_t)v.x, (bf16_t)v.y, (bf16_t)v.z, (bf16_t)v.w};
    ((bf16x4*)out)[i] = o;
  }
}

// out[H][B] = transpose(in[B][H]);  H=2048, B=4096; 32x32 LDS tiles
__global__ void transpose_f32(const float* __restrict__ in,
                              float* __restrict__ out) {
  __shared__ float t[32][33];
  const int c0 = blockIdx.x * 32;  // H index
  const int r0 = blockIdx.y * 32;  // B index
  const int tx = threadIdx.x & 31;
  const int ty = threadIdx.x >> 5;  // 0..7
#pragma unroll
  for (int j = 0; j < 32; j += 8)
    t[ty + j][tx] = in[(long)(r0 + ty + j) * 2048 + c0 + tx];
  __syncthreads();
#pragma unroll
  for (int j = 0; j < 32; j += 8)
    out[(long)(c0 + ty + j) * 4096 + r0 + tx] = t[tx][ty + j];
}

// C[M,N] = A[M,K] * B[N,K]^T   (NT, both row-major, K contiguous)
// VGPR-staged, register-double-buffered K-loop (hipBLASLt/AITER pattern):
//  - prefetch tile k+1 into 8 bf16x8 regs/wave via ordinary global loads
//    (issued BEFORE the barrier -> ~a full iteration in flight; allocates
//    in L2, unlike the global_load_lds DMA path whose ~4-deep per-CU queue
//    capped rounds 1-6 at ~10 B/cyc/CU)
//  - ONE raw s_barrier per iter with explicit lgkmcnt(0) only: prefetch
//    loads stay in flight across the barrier (vmcnt never force-drained)
//  - ds_write_b128 into dbuf LDS after compute; compiler inserts the vmcnt
//    wait for the regs right there (after compute = the pipeline win)
// LDS chunk layout (verified 0 conflicts): 16-row x 32-col 1 KB chunks;
// lane -> row = lane&15, kcol = (lane>>4)*8; chunk (rg,ks) at (rg*2+ks)*512.
// EPI=0: ihbT[col][row] = acc + bias1[col] + bias2[col]
// EPI=1: pre = acc + ihbT; hn = d*hT + (1-d)*tanh(pre); hT = hn (float4);
//        hb_next[row][col] = bf16(hn);  last step: out[row][col] = hn
template <int EPI>
__global__ __launch_bounds__(256, 2) void gemm_nt(
    const bf16_t* __restrict__ A, const bf16_t* __restrict__ Bw, int M, int N,
    int K, const float* __restrict__ bias1, const float* __restrict__ bias2,
    bf16_t* __restrict__ ihbT_out, const bf16_t* __restrict__ ihbT,
    const float* __restrict__ tau, float* __restrict__ hT,
    bf16_t* __restrict__ hb_next, float* __restrict__ out, int writeOut) {
  __shared__ __align__(16) bf16_t As[2][128 * BK];  // 2 x 16 KB
  __shared__ __align__(16) bf16_t Bs[2][128 * BK];  // 2 x 16 KB

  const int tid = threadIdx.x;
  const int lane = tid & 63;
  const int wave = tid >> 6;     // 0..3
  const int waveM = wave >> 1;   // 0..1  (64-row half)
  const int waveN = wave & 1;    // 0..1  (64-col half)

  // XCD swizzle (verified: FETCH 135->64 MB): 8x8 tile sub-grid per XCD
  const int lin = blockIdx.y * gridDim.x + blockIdx.x;  // 0..511
  const int xcd = lin & 7;
  const int slot = lin >> 3;                   // 0..63
  const int bx = (xcd & 1) * 8 + (slot & 7);   // 0..15
  const int by = (xcd >> 1) * 8 + (slot >> 3); // 0..31
  const long bRow = (long)by * 128;
  const long bCol = (long)bx * 128;

  // staging: wave w covers rowgroups {2w, 2w+1} (rows w*32..w*32+32) x
  // kslices {0,1} for both operands; lane -> row = lane&15, kcol=(lane>>4)*8
  const int laneRow = lane & 15;
  const int laneK = (lane >> 4) << 3;
  const bf16_t* aG = A + (bRow + wave * 32 + laneRow) * (long)K + laneK;
  const bf16_t* bG = Bw + (bCol + wave * 32 + laneRow) * (long)K + laneK;

  bf16x8 ra[4], rb[4];
  auto loadRegs = [&](long k0) {
#pragma unroll
    for (int r = 0; r < 2; ++r)
#pragma unroll
      for (int ks = 0; ks < 2; ++ks) {
        ra[r * 2 + ks] = *(const bf16x8*)(aG + (long)r * 16 * K + k0 + ks * 32);
        rb[r * 2 + ks] = *(const bf16x8*)(bG + (long)r * 16 * K + k0 + ks * 32);
      }
  };
  auto storeLDS = [&](int p) {
#pragma unroll
    for (int r = 0; r < 2; ++r)
#pragma unroll
      for (int ks = 0; ks < 2; ++ks) {
        const int off = ((wave * 2 + r) * 2 + ks) * 512 + lane * 8;
        *(bf16x8*)&As[p][off] = ra[r * 2 + ks];
        *(bf16x8*)&Bs[p][off] = rb[r * 2 + ks];
      }
  };

  f32x4 acc[4][4] = {};
  const int nIter = K / BK;

  loadRegs(0);
  storeLDS(0);  // compiler waits vmcnt for ra/rb right before these writes
  int p = 0;
  for (int i = 0; i < nIter; ++i) {
    if (i + 1 < nIter) loadRegs((long)(i + 1) * BK);  // prefetch, stays in flight
    // drain own ds ops (writes of tile i / reads of tile i-1), then raw
    // barrier: buf[p] is complete across waves; prefetch vmcnt NOT drained
    asm volatile("s_waitcnt lgkmcnt(0)" ::: "memory");
    __builtin_amdgcn_s_barrier();

#pragma unroll
    for (int ks = 0; ks < 2; ++ks) {
      bf16x8 aF[4], bF[4];
#pragma unroll
      for (int t = 0; t < 4; ++t)
        aF[t] = *(const bf16x8*)&As[p][((waveM * 4 + t) * 2 + ks) * 512 + lane * 8];
#pragma unroll
      for (int u = 0; u < 4; ++u)
        bF[u] = *(const bf16x8*)&Bs[p][((waveN * 4 + u) * 2 + ks) * 512 + lane * 8];
#pragma unroll
      for (int t = 0; t < 4; ++t)
#pragma unroll
        for (int u = 0; u < 4; ++u)
          acc[t][u] = __builtin_amdgcn_mfma_f32_16x16x32_bf16(
              aF[t], bF[u], acc[t][u], 0, 0, 0);
    }
    if (i + 1 < nIter) storeLDS(p ^ 1);  // write NEXT buffer; no race with
                                         // peers still reading buf[p]
    p ^= 1;
  }

  // C/D layout: col = lane&15, row = (lane>>4)*4 + reg   [measured m89/m91]
  const int eRow = (lane >> 4) << 2;
  const int eCol = lane & 15;

  if (EPI == 0) {
#pragma unroll
    for (int u = 0; u < 4; ++u) {
      const int col = (int)bCol + waveN * 64 + u * 16 + eCol;
      const float bb = bias1[col] + bias2[col];
#pragma unroll
      for (int t = 0; t < 4; ++t) {
        const long row = bRow + waveM * 64 + t * 16 + eRow;
        const long iT = (long)col * M + row;
        bf16x4 o;
#pragma unroll
        for (int r = 0; r < 4; ++r) o[r] = (bf16_t)(acc[t][u][r] + bb);
        *(bf16x4*)&ihbT_out[iT] = o;
      }
    }
  } else {
#pragma unroll
    for (int u = 0; u < 4; ++u) {
      const int col = (int)bCol + waveN * 64 + u * 16 + eCol;
      const float dcy = __expf(-DT / tau[col]);
#pragma unroll
      for (int t = 0; t < 4; ++t) {
        const long row = bRow + waveM * 64 + t * 16 + eRow;
        const long iT = (long)col * M + row;
        const f32x4 hp = *(const f32x4*)&hT[iT];
        const bf16x4 ih4 = *(const bf16x4*)&ihbT[iT];
        float hn[4];
#pragma unroll
        for (int r = 0; r < 4; ++r) {
          const float pre = acc[t][u][r] + (float)ih4[r];
          const float th = tanhf(pre);
          hn[r] = dcy * hp[r] + (1.0f - dcy) * th;
        }
        if (!writeOut) {
          f32x4 hv = {hn[0], hn[1], hn[2], hn[3]};
          *(f32x4*)&hT[iT] = hv;
#pragma unroll
          for (int r = 0; r < 4; ++r)
            hb_next[(row + r) * (long)N + col] = (bf16_t)hn[r];
        } else {
#pragma unroll
          for (int r = 0; r < 4; ++r)
            out[(row + r) * (long)N + col] = hn[r];
        }
      }
    }
  }
}

extern "C" void kernel_launch(void* const* d_in, const int* in_sizes, int n_in,
                              void* d_out, int out_size, void* d_ws,
                              size_t ws_size, hipStream_t stream) {
  const float* x = (const float*)d_in[0];
  const float* h0 = (const float*)d_in[1];
  const float* W_ih = (const float*)d_in[2];
  const float* b_ih = (const float*)d_in[3];
  const float* W_hh = (const float*)d_in[4];
  const float* b_hh = (const float*)d_in[5];
  const float* tau = (const float*)d_in[6];
  float* hout = (float*)d_out;

  const int B = 4096, I = 1024, H = 2048;

  char* ws = (char*)d_ws;
  bf16_t* ihbT = (bf16_t*)ws; ws += (size_t)B * H * 2;  // 16 MB  [H][B]
  float* hT = (float*)ws;     ws += (size_t)B * H * 4;  // 32 MB  [H][B]
  bf16_t* hb0 = (bf16_t*)ws;  ws += (size_t)B * H * 2;  // 16 MB  [B][H]
  bf16_t* hb1 = (bf16_t*)ws;  ws += (size_t)B * H * 2;  // 16 MB  [B][H]
  bf16_t* xb = (bf16_t*)ws;   ws += (size_t)B * I * 2;  // 8 MB
  bf16_t* wihb = (bf16_t*)ws; ws += (size_t)H * I * 2;  // 4 MB
  bf16_t* whhb = (bf16_t*)ws; ws += (size_t)H * H * 2;  // 8 MB

  cvt_f32_to_bf16<<<(B * I / 4 + 255) / 256, 256, 0, stream>>>(x, xb, B * I / 4);
  cvt_f32_to_bf16<<<(H * I / 4 + 255) / 256, 256, 0, stream>>>(W_ih, wihb, H * I / 4);
  cvt_f32_to_bf16<<<(H * H / 4 + 255) / 256, 256, 0, stream>>>(W_hh, whhb, H * H / 4);
  cvt_f32_to_bf16<<<(B * H / 4 + 255) / 256, 256, 0, stream>>>(h0, hb0, B * H / 4);
  transpose_f32<<<dim3(H / 32, B / 32), 256, 0, stream>>>(h0, hT);

  dim3 grid(H / 128, B / 128);  // (16, 32) = 512 blocks, 2/CU
  // ihbT = (x @ W_ih^T + b_ih + b_hh)^T   (fold both biases once, bf16)
  gemm_nt<0><<<grid, 256, 0, stream>>>(xb, wihb, B, H, I, b_ih, b_hh, ihbT,
                                       nullptr, nullptr, nullptr, nullptr,
                                       nullptr, 0);

  bf16_t* hb[2] = {hb0, hb1};
  for (int s = 0; s < NUM_STEPS; ++s) {
    gemm_nt<1><<<grid, 256, 0, stream>>>(
        hb[s & 1], whhb, B, H, H, nullptr, nullptr, nullptr, ihbT, tau, hT,
        hb[(s + 1) & 1], hout, (s == NUM_STEPS - 1) ? 1 : 0);
  }
}